// Round 5
// baseline (704.565 us; speedup 1.0000x reference)
//
#include <hip/hip_runtime.h>

#define BATCH 512
#define SEQ   512
#define IN    28
#define HID   128
#define NCLS  10
#define ROWS  2
// h layout: 16 chunks of 8 floats, each chunk padded to 12 -> slice reads are 2-way bank aliased (free)
#define PADDR(k)  ((((k) >> 3) * 12) + ((k) & 7))
#define HSTRIDE   (16 * 12)   // 192 floats per row

__device__ __forceinline__ float fast_tanh(float x) {
    float e = __expf(2.0f * x);
    return 1.0f - 2.0f * __builtin_amdgcn_rcpf(e + 1.0f);
}

template<int CTRL>
__device__ __forceinline__ float dpp_add(float v) {
    int n = __builtin_amdgcn_update_dpp(0, __float_as_int(v), CTRL, 0xF, 0xF, true);
    return v + __int_as_float(n);
}
// 16-lane reduce; valid in lane 0 of each 16-row.
// DPP row_ror:N reads lane (i-N)&15 == lane (i + (16-N))&15 (verified R4: ror12 pulls +4).
__device__ __forceinline__ float reduce16(float v) {
    v = dpp_add<0xB1>(v);     // quad_perm xor1
    v = dpp_add<0x4E>(v);     // quad_perm xor2
    v = dpp_add<0x12C>(v);    // row_ror:12 -> lane i += lane (i+4)&15
    v = dpp_add<0x128>(v);    // row_ror:8  -> lane i += lane (i+8)&15
    return v;
}

__global__ __launch_bounds__(1024)
void rnn2_kernel(const float* __restrict__ x,
                 const float* __restrict__ W_ih0, const float* __restrict__ W_hh0,
                 const float* __restrict__ b_ih0, const float* __restrict__ b_hh0,
                 const float* __restrict__ W_ih1, const float* __restrict__ W_hh1,
                 const float* __restrict__ b_ih1, const float* __restrict__ b_hh1,
                 const float* __restrict__ W_fc,  const float* __restrict__ b_fc,
                 float* __restrict__ out)
{
    __shared__ __align__(16) float h0buf[2][ROWS][HSTRIDE];
    __shared__ __align__(16) float h1buf[2][ROWS][HSTRIDE];

    const int t  = threadIdx.x;   // 0..1023
    const int g  = t >> 4;        // unit-group 0..63 -> units 2g, 2g+1
    const int sl = t & 15;        // k-slice 0..15 (8 k each for hh parts)
    const int j0 = 2 * g;
    const int hk = 8 * sl;

    // ---- weights in VGPRs: 2x8 x3 (hh0, ih1, hh1) + 2x2 (ih0) = 52 floats
    float whh0[2][8], wih1[2][8], whh1[2][8], wih0[2][2];
    #pragma unroll
    for (int u = 0; u < 2; ++u) {
        const float* p0 = W_hh0 + (j0 + u) * HID + hk;
        const float* p1 = W_ih1 + (j0 + u) * HID + hk;
        const float* p2 = W_hh1 + (j0 + u) * HID + hk;
        #pragma unroll
        for (int k = 0; k < 8; ++k) {
            whh0[u][k] = p0[k];
            wih1[u][k] = p1[k];
            whh1[u][k] = p2[k];
        }
    }
    // x part: slices 0..13 own k = 2sl, 2sl+1 (covers 0..27); 14,15 idle (zero weights)
    const int xk = (sl < 14) ? 2 * sl : 26;   // clamp keeps loads in-bounds
    #pragma unroll
    for (int u = 0; u < 2; ++u) {
        #pragma unroll
        for (int kk = 0; kk < 2; ++kk)
            wih0[u][kk] = (sl < 14) ? W_ih0[(j0 + u) * IN + xk + kk] : 0.0f;
    }
    const float bias0_0 = b_ih0[j0] + b_hh0[j0];
    const float bias0_1 = b_ih0[j0 + 1] + b_hh0[j0 + 1];
    const float bias1_0 = b_ih1[j0] + b_hh1[j0];
    const float bias1_1 = b_ih1[j0 + 1] + b_hh1[j0 + 1];

    if (t < HSTRIDE) {
        #pragma unroll
        for (int r = 0; r < ROWS; ++r) {
            h0buf[0][r][t] = 0.0f;
            h1buf[0][r][t] = 0.0f;
        }
    }

    // ---- x: direct global reads (float2 per slice), prefetched one step ahead
    const float* xrow[ROWS];
    float2 xcur[ROWS];
    #pragma unroll
    for (int r = 0; r < ROWS; ++r) {
        xrow[r] = x + ((size_t)(blockIdx.x * ROWS + r) * SEQ) * IN + xk;
        xcur[r] = *(const float2*)(xrow[r]);
    }

    __syncthreads();

    const int ws0 = PADDR(j0);    // write slot (j0, j0+1 are adjacent in the same chunk)

    for (int step = 0; step < SEQ; ++step) {
        const int rd = step & 1, wr = rd ^ 1;
        const int nxt = (step < SEQ - 1) ? (step + 1) * IN : step * IN;

        // ---- phase A: h0 = tanh(Wih0 x + Whh0 h0_prev + b)
        float redA0[ROWS], redA1[ROWS];
        #pragma unroll
        for (int r = 0; r < ROWS; ++r) {
            float2 xn = *(const float2*)(xrow[r] + nxt);
            const float4* hp = (const float4*)&h0buf[rd][r][12 * sl];
            float4 hA = hp[0], hB = hp[1];

            float a0 = wih0[0][0] * xcur[r].x;
            float b0 = wih0[0][1] * xcur[r].y;
            float a1 = wih0[1][0] * xcur[r].x;
            float b1 = wih0[1][1] * xcur[r].y;
            a0 = fmaf(whh0[0][0], hA.x, a0); b0 = fmaf(whh0[0][1], hA.y, b0);
            a0 = fmaf(whh0[0][2], hA.z, a0); b0 = fmaf(whh0[0][3], hA.w, b0);
            a0 = fmaf(whh0[0][4], hB.x, a0); b0 = fmaf(whh0[0][5], hB.y, b0);
            a0 = fmaf(whh0[0][6], hB.z, a0); b0 = fmaf(whh0[0][7], hB.w, b0);
            a1 = fmaf(whh0[1][0], hA.x, a1); b1 = fmaf(whh0[1][1], hA.y, b1);
            a1 = fmaf(whh0[1][2], hA.z, a1); b1 = fmaf(whh0[1][3], hA.w, b1);
            a1 = fmaf(whh0[1][4], hB.x, a1); b1 = fmaf(whh0[1][5], hB.y, b1);
            a1 = fmaf(whh0[1][6], hB.z, a1); b1 = fmaf(whh0[1][7], hB.w, b1);

            redA0[r] = reduce16(a0 + b0);
            redA1[r] = reduce16(a1 + b1);
            xcur[r] = xn;
        }
        if (sl == 0) {
            #pragma unroll
            for (int r = 0; r < ROWS; ++r) {
                float2 hv;
                hv.x = fast_tanh(redA0[r] + bias0_0);
                hv.y = fast_tanh(redA1[r] + bias0_1);
                *(float2*)&h0buf[wr][r][ws0] = hv;
            }
        }
        __syncthreads();

        // ---- phase B: h1 = tanh(Wih1 h0_new + Whh1 h1_prev + b)
        float redB0[ROWS], redB1[ROWS];
        #pragma unroll
        for (int r = 0; r < ROWS; ++r) {
            const float4* gp = (const float4*)&h0buf[wr][r][12 * sl];
            const float4* hp = (const float4*)&h1buf[rd][r][12 * sl];
            float4 gA = gp[0], gB = gp[1];
            float4 hA = hp[0], hB = hp[1];

            float a0 = wih1[0][0] * gA.x;
            float b0 = wih1[0][1] * gA.y;
            float a1 = wih1[1][0] * gA.x;
            float b1 = wih1[1][1] * gA.y;
            a0 = fmaf(wih1[0][2], gA.z, a0); b0 = fmaf(wih1[0][3], gA.w, b0);
            a0 = fmaf(wih1[0][4], gB.x, a0); b0 = fmaf(wih1[0][5], gB.y, b0);
            a0 = fmaf(wih1[0][6], gB.z, a0); b0 = fmaf(wih1[0][7], gB.w, b0);
            a1 = fmaf(wih1[1][2], gA.z, a1); b1 = fmaf(wih1[1][3], gA.w, b1);
            a1 = fmaf(wih1[1][4], gB.x, a1); b1 = fmaf(wih1[1][5], gB.y, b1);
            a1 = fmaf(wih1[1][6], gB.z, a1); b1 = fmaf(wih1[1][7], gB.w, b1);

            a0 = fmaf(whh1[0][0], hA.x, a0); b0 = fmaf(whh1[0][1], hA.y, b0);
            a0 = fmaf(whh1[0][2], hA.z, a0); b0 = fmaf(whh1[0][3], hA.w, b0);
            a0 = fmaf(whh1[0][4], hB.x, a0); b0 = fmaf(whh1[0][5], hB.y, b0);
            a0 = fmaf(whh1[0][6], hB.z, a0); b0 = fmaf(whh1[0][7], hB.w, b0);
            a1 = fmaf(whh1[1][0], hA.x, a1); b1 = fmaf(whh1[1][1], hA.y, b1);
            a1 = fmaf(whh1[1][2], hA.z, a1); b1 = fmaf(whh1[1][3], hA.w, b1);
            a1 = fmaf(whh1[1][4], hB.x, a1); b1 = fmaf(whh1[1][5], hB.y, b1);
            a1 = fmaf(whh1[1][6], hB.z, a1); b1 = fmaf(whh1[1][7], hB.w, b1);

            redB0[r] = reduce16(a0 + b0);
            redB1[r] = reduce16(a1 + b1);
        }
        if (sl == 0) {
            #pragma unroll
            for (int r = 0; r < ROWS; ++r) {
                float2 hv;
                hv.x = fast_tanh(redB0[r] + bias1_0);
                hv.y = fast_tanh(redB1[r] + bias1_1);
                *(float2*)&h1buf[wr][r][ws0] = hv;
            }
        }
        __syncthreads();
    }

    // ---- fc epilogue: final h1 in buffer 0 (step 511: wr = 0)
    if (t < ROWS * NCLS) {
        const int r = t / NCLS, c = t % NCLS;
        float acc = b_fc[c];
        const float* wf = W_fc + c * HID;
        #pragma unroll 4
        for (int k = 0; k < HID; ++k)
            acc = fmaf(wf[k], h1buf[0][r][PADDR(k)], acc);
        out[(blockIdx.x * ROWS + r) * NCLS + c] = acc;
    }
}

extern "C" void kernel_launch(void* const* d_in, const int* in_sizes, int n_in,
                              void* d_out, int out_size, void* d_ws, size_t ws_size,
                              hipStream_t stream) {
    const float* x     = (const float*)d_in[0];
    const float* W_ih0 = (const float*)d_in[1];
    const float* W_hh0 = (const float*)d_in[2];
    const float* b_ih0 = (const float*)d_in[3];
    const float* b_hh0 = (const float*)d_in[4];
    const float* W_ih1 = (const float*)d_in[5];
    const float* W_hh1 = (const float*)d_in[6];
    const float* b_ih1 = (const float*)d_in[7];
    const float* b_hh1 = (const float*)d_in[8];
    const float* W_fc  = (const float*)d_in[9];
    const float* b_fc  = (const float*)d_in[10];
    float* out = (float*)d_out;

    rnn2_kernel<<<dim3(BATCH / ROWS), dim3(1024), 0, stream>>>(
        x, W_ih0, W_hh0, b_ih0, b_hh0, W_ih1, W_hh1, b_ih1, b_hh1, W_fc, b_fc, out);
}

// Round 6
// 518.233 us; speedup vs baseline: 1.3596x; 1.3596x over previous
//
#include <hip/hip_runtime.h>

#define BATCH 512
#define SEQ   512
#define IN    28
#define HID   128
#define NCLS  10
#define ROWS  2
#define PAD20(k) (((k) >> 4) * 20 + ((k) & 15))   // 16-float slice padded to 20 (R4-verified conflict-free)

__device__ __forceinline__ float fast_tanh(float x) {
    float e = __expf(2.0f * x);
    return 1.0f - 2.0f * __builtin_amdgcn_rcpf(e + 1.0f);
}

template<int CTRL>
__device__ __forceinline__ float dpp_add(float v) {
    int n = __builtin_amdgcn_update_dpp(0, __float_as_int(v), CTRL, 0xF, 0xF, true);
    return v + __int_as_float(n);
}
// 8-lane reduce; valid in lane sl==0 of each 8-group (R4-verified).
// DPP row_ror:N reads lane (i-N)&15, so ror12 pulls lane (i+4)&15.
__device__ __forceinline__ float reduce8(float v) {
    v = dpp_add<0xB1>(v);     // quad_perm xor1
    v = dpp_add<0x4E>(v);     // quad_perm xor2
    v = dpp_add<0x12C>(v);    // row_ror:12 -> lane i += lane (i+4)&15
    return v;
}

__global__ __launch_bounds__(1024)
void rnn2_kernel(const float* __restrict__ x,
                 const float* __restrict__ W_ih0, const float* __restrict__ W_hh0,
                 const float* __restrict__ b_ih0, const float* __restrict__ b_hh0,
                 const float* __restrict__ W_ih1, const float* __restrict__ W_hh1,
                 const float* __restrict__ b_ih1, const float* __restrict__ b_hh1,
                 const float* __restrict__ W_fc,  const float* __restrict__ b_fc,
                 float* __restrict__ out)
{
    __shared__ __align__(16) float h0buf[2][ROWS][8 * 20];
    __shared__ __align__(16) float h1buf[2][ROWS][8 * 20];

    const int t  = threadIdx.x;      // 0..1023
    const int j  = t >> 3;           // unit 0..127
    const int sl = t & 7;            // k-slice 0..7 (16 k each)

    // ---- weights: 4 + 16 + 16 + 16 = 52 floats/thread
    float wih0[4], whh0[16], wih1[16], whh1[16];
    if (sl < 7) {
        const float* p = W_ih0 + j * IN + sl * 4;
        #pragma unroll
        for (int k = 0; k < 4; ++k) wih0[k] = p[k];
    } else {
        #pragma unroll
        for (int k = 0; k < 4; ++k) wih0[k] = 0.0f;
    }
    {
        const float* p0 = W_hh0 + j * HID + sl * 16;
        const float* p1 = W_ih1 + j * HID + sl * 16;
        const float* p2 = W_hh1 + j * HID + sl * 16;
        #pragma unroll
        for (int k = 0; k < 16; ++k) {
            whh0[k] = p0[k];
            wih1[k] = p1[k];
            whh1[k] = p2[k];
        }
    }
    const float bias0 = b_ih0[j] + b_hh0[j];
    const float bias1 = b_ih1[j] + b_hh1[j];

    if (t < 8 * 20) {
        #pragma unroll
        for (int r = 0; r < ROWS; ++r) {
            h0buf[0][r][t] = 0.0f;
            h1buf[0][r][t] = 0.0f;
        }
    }

    // ---- x: direct global reads, prefetched one iteration ahead
    const int xoff = (sl < 7) ? sl * 4 : 0;      // sl==7 has zero weights; clamp in-bounds
    const float* xrow[ROWS];
    float4 xcur[ROWS];
    #pragma unroll
    for (int r = 0; r < ROWS; ++r) {
        xrow[r] = x + ((size_t)(blockIdx.x * ROWS + r) * SEQ) * IN + xoff;
        xcur[r] = *(const float4*)(xrow[r]);     // x(0)
    }

    __syncthreads();

    const int wslot = PAD20(j);

    // ---- pipelined time loop: iteration it computes h0(it) AND h1(it-1); one barrier each.
    //   A: h0(it)   = tanh(Wih0·x(it)   + Whh0·h0(it-1) + b0)   [garbage at it=SEQ, unused]
    //   B: h1(it-1) = tanh(Wih1·h0(it-1) + Whh1·h1(it-2) + b1)  [forced 0 at it=0]
    for (int it = 0; it <= SEQ; ++it) {
        const int rd = it & 1, wr = rd ^ 1;
        const int nxtoff = ((it < SEQ - 1) ? (it + 1) : (SEQ - 1)) * IN;

        float redA[ROWS], redB[ROWS];
        #pragma unroll
        for (int r = 0; r < ROWS; ++r) {
            float4 xn = *(const float4*)(xrow[r] + nxtoff);   // prefetch x(it+1)

            const float4* h0p = (const float4*)&h0buf[rd][r][sl * 20];
            const float4* h1p = (const float4*)&h1buf[rd][r][sl * 20];
            float4 p0 = h0p[0], p1 = h0p[1], p2 = h0p[2], p3 = h0p[3];
            float4 q0 = h1p[0], q1 = h1p[1], q2 = h1p[2], q3 = h1p[3];

            // A-chain: Wih0·x + Whh0·h0_prev
            float a0 = wih0[0] * xcur[r].x;
            float a1 = wih0[1] * xcur[r].y;
            float a2 = wih0[2] * xcur[r].z;
            float a3 = wih0[3] * xcur[r].w;
            a0 = fmaf(whh0[ 0], p0.x, a0); a1 = fmaf(whh0[ 1], p0.y, a1);
            a2 = fmaf(whh0[ 2], p0.z, a2); a3 = fmaf(whh0[ 3], p0.w, a3);
            a0 = fmaf(whh0[ 4], p1.x, a0); a1 = fmaf(whh0[ 5], p1.y, a1);
            a2 = fmaf(whh0[ 6], p1.z, a2); a3 = fmaf(whh0[ 7], p1.w, a3);
            a0 = fmaf(whh0[ 8], p2.x, a0); a1 = fmaf(whh0[ 9], p2.y, a1);
            a2 = fmaf(whh0[10], p2.z, a2); a3 = fmaf(whh0[11], p2.w, a3);
            a0 = fmaf(whh0[12], p3.x, a0); a1 = fmaf(whh0[13], p3.y, a1);
            a2 = fmaf(whh0[14], p3.z, a2); a3 = fmaf(whh0[15], p3.w, a3);

            // B-chain: Wih1·h0_prev + Whh1·h1_prev2
            float c0, c1, c2, c3;
            c0 = wih1[0] * p0.x;           c1 = wih1[1] * p0.y;
            c2 = wih1[2] * p0.z;           c3 = wih1[3] * p0.w;
            c0 = fmaf(wih1[ 4], p1.x, c0); c1 = fmaf(wih1[ 5], p1.y, c1);
            c2 = fmaf(wih1[ 6], p1.z, c2); c3 = fmaf(wih1[ 7], p1.w, c3);
            c0 = fmaf(wih1[ 8], p2.x, c0); c1 = fmaf(wih1[ 9], p2.y, c1);
            c2 = fmaf(wih1[10], p2.z, c2); c3 = fmaf(wih1[11], p2.w, c3);
            c0 = fmaf(wih1[12], p3.x, c0); c1 = fmaf(wih1[13], p3.y, c1);
            c2 = fmaf(wih1[14], p3.z, c2); c3 = fmaf(wih1[15], p3.w, c3);
            c0 = fmaf(whh1[ 0], q0.x, c0); c1 = fmaf(whh1[ 1], q0.y, c1);
            c2 = fmaf(whh1[ 2], q0.z, c2); c3 = fmaf(whh1[ 3], q0.w, c3);
            c0 = fmaf(whh1[ 4], q1.x, c0); c1 = fmaf(whh1[ 5], q1.y, c1);
            c2 = fmaf(whh1[ 6], q1.z, c2); c3 = fmaf(whh1[ 7], q1.w, c3);
            c0 = fmaf(whh1[ 8], q2.x, c0); c1 = fmaf(whh1[ 9], q2.y, c1);
            c2 = fmaf(whh1[10], q2.z, c2); c3 = fmaf(whh1[11], q2.w, c3);
            c0 = fmaf(whh1[12], q3.x, c0); c1 = fmaf(whh1[13], q3.y, c1);
            c2 = fmaf(whh1[14], q3.z, c2); c3 = fmaf(whh1[15], q3.w, c3);

            redA[r] = reduce8((a0 + a2) + (a1 + a3));
            redB[r] = reduce8((c0 + c2) + (c1 + c3));
            xcur[r] = xn;
        }

        if (sl == 0) {
            #pragma unroll
            for (int r = 0; r < ROWS; ++r) {
                h0buf[wr][r][wslot] = fast_tanh(redA[r] + bias0);
                h1buf[wr][r][wslot] = (it == 0) ? 0.0f
                                                : fast_tanh(redB[r] + bias1);
            }
        }
        __syncthreads();
    }

    // ---- fc epilogue: it=SEQ wrote h1(511) into buffer wr = (SEQ&1)^1 = 1
    if (t < ROWS * NCLS) {
        const int r = t / NCLS, c = t % NCLS;
        float acc = b_fc[c];
        const float* wf = W_fc + c * HID;
        #pragma unroll 4
        for (int k = 0; k < HID; ++k)
            acc = fmaf(wf[k], h1buf[1][r][PAD20(k)], acc);
        out[(blockIdx.x * ROWS + r) * NCLS + c] = acc;
    }
}

extern "C" void kernel_launch(void* const* d_in, const int* in_sizes, int n_in,
                              void* d_out, int out_size, void* d_ws, size_t ws_size,
                              hipStream_t stream) {
    const float* x     = (const float*)d_in[0];
    const float* W_ih0 = (const float*)d_in[1];
    const float* W_hh0 = (const float*)d_in[2];
    const float* b_ih0 = (const float*)d_in[3];
    const float* b_hh0 = (const float*)d_in[4];
    const float* W_ih1 = (const float*)d_in[5];
    const float* W_hh1 = (const float*)d_in[6];
    const float* b_ih1 = (const float*)d_in[7];
    const float* b_hh1 = (const float*)d_in[8];
    const float* W_fc  = (const float*)d_in[9];
    const float* b_fc  = (const float*)d_in[10];
    float* out = (float*)d_out;

    rnn2_kernel<<<dim3(BATCH / ROWS), dim3(1024), 0, stream>>>(
        x, W_ih0, W_hh0, b_ih0, b_hh0, W_ih1, W_hh1, b_ih1, b_hh1, W_fc, b_fc, out);
}